// Round 1
// baseline (1163.705 us; speedup 1.0000x reference)
//
#include <hip/hip_runtime.h>

// Problem constants (from reference): Q=512 states, S=64 symbols, B=64, T=256.
#define QN 512
#define SN 64
#define BN 64
#define TN 256

// ---- int8 dot4 (v_dot4_i32_i8) with software fallback ----
#if defined(__has_builtin)
#if __has_builtin(__builtin_amdgcn_sdot4)
#define SDOT4(a, b, c) __builtin_amdgcn_sdot4((a), (b), (c), false)
#endif
#endif
#ifndef SDOT4
static __device__ __forceinline__ int sdot4_sw(int a, int b, int c) {
    c += (int)(signed char)(a)       * (int)(signed char)(b);
    c += (int)(signed char)(a >> 8)  * (int)(signed char)(b >> 8);
    c += (int)(signed char)(a >> 16) * (int)(signed char)(b >> 16);
    c += (int)(signed char)(a >> 24) * (int)(signed char)(b >> 24);
    return c;
}
#define SDOT4(a, b, c) sdot4_sw((a), (b), (c))
#endif

static __device__ __forceinline__ float wave_sum(float v) {
    #pragma unroll
    for (int o = 32; o > 0; o >>= 1) v += __shfl_xor(v, o, 64);
    return v;
}
static __device__ __forceinline__ float wave_max(float v) {
    #pragma unroll
    for (int o = 32; o > 0; o >>= 1) v = fmaxf(v, __shfl_xor(v, o, 64));
    return v;
}

// ---- Kernel A: per-symbol absmax of E = exp(A) - 1/Q ----
// A layout: A[i][s][j], row (i*64+s) is 512 contiguous floats. One wave per row.
__global__ __launch_bounds__(512) void k_absmax(const float* __restrict__ A,
                                                unsigned* __restrict__ smax) {
    const int wave = threadIdx.x >> 6, lane = threadIdx.x & 63;
    const int row = blockIdx.x * 8 + wave;          // 0 .. 32767 = i*64 + s
    const float4* Af = (const float4*)A + (size_t)row * 128;
    const float c = 1.0f / 512.0f;
    float4 a = Af[lane];
    float4 b = Af[lane + 64];
    float mx = fabsf(expf(a.x) - c);
    mx = fmaxf(mx, fabsf(expf(a.y) - c));
    mx = fmaxf(mx, fabsf(expf(a.z) - c));
    mx = fmaxf(mx, fabsf(expf(a.w) - c));
    mx = fmaxf(mx, fabsf(expf(b.x) - c));
    mx = fmaxf(mx, fabsf(expf(b.y) - c));
    mx = fmaxf(mx, fabsf(expf(b.z) - c));
    mx = fmaxf(mx, fabsf(expf(b.w) - c));
    mx = wave_max(mx);
    if (lane == 0) atomicMax(&smax[row & 63], __float_as_uint(mx));
}

// ---- Kernel B: quantize E to int8, pack transposed layout + rowsums ----
// Output Epk (int32 units): index ((s*32 + j16)*512 + i)*4 + w holds bytes for
// j = 16*j16 + 4*w + {0..3} at state i  -> int4 load = 16 consecutive j for one i,
// consecutive lanes i => 1 KiB contiguous per wave inst.
__global__ __launch_bounds__(256) void k_quant(const float* __restrict__ A,
                                               const unsigned* __restrict__ smax,
                                               int* __restrict__ Epk,
                                               int* __restrict__ R) {
    __shared__ int tile[64][129];                    // [i_local][j4], padded
    const int s  = blockIdx.x >> 3;
    const int i0 = (blockIdx.x & 7) * 64;
    const float se  = __uint_as_float(smax[s]);
    const float inv = se > 0.0f ? 127.0f / se : 0.0f;
    const float c = 1.0f / 512.0f;
    const int tl = threadIdx.x & 127;                // j4 within row
    const int rh = threadIdx.x >> 7;                 // row parity
    for (int ro = 0; ro < 64; ro += 2) {
        const int r = ro + rh;
        const int i = i0 + r;
        float4 a4 = ((const float4*)A)[(size_t)(i * 64 + s) * 128 + tl];
        int q0 = (int)rintf(fminf(fmaxf((expf(a4.x) - c) * inv, -127.0f), 127.0f));
        int q1 = (int)rintf(fminf(fmaxf((expf(a4.y) - c) * inv, -127.0f), 127.0f));
        int q2 = (int)rintf(fminf(fmaxf((expf(a4.z) - c) * inv, -127.0f), 127.0f));
        int q3 = (int)rintf(fminf(fmaxf((expf(a4.w) - c) * inv, -127.0f), 127.0f));
        tile[r][tl] = (q0 & 255) | ((q1 & 255) << 8) | ((q2 & 255) << 16) | ((q3 & 255) << 24);
    }
    __syncthreads();
    // rowsums over quantized values (exact)
    if (threadIdx.x < 64) {
        const int r = threadIdx.x;
        int acc = 0;
        #pragma unroll 8
        for (int k = 0; k < 128; ++k) acc = SDOT4(tile[r][k], 0x01010101, acc);
        R[(s << 9) + i0 + r] = acc;
    }
    // packed stores: int4 per (j16, i)
    const int il = threadIdx.x & 63;
    const int jg = threadIdx.x >> 6;                 // 0..3
    for (int jo = 0; jo < 8; ++jo) {
        const int j16 = jg * 8 + jo;                 // 0..31
        int4 v;
        v.x = tile[il][j16 * 4 + 0];
        v.y = tile[il][j16 * 4 + 1];
        v.z = tile[il][j16 * 4 + 2];
        v.w = tile[il][j16 * 4 + 3];
        ((int4*)Epk)[((size_t)(s * 32 + j16) * 512) + i0 + il] = v;
    }
}

// ---- Main kernel: one block per batch, whole T-chain in-block ----
__global__ __launch_bounds__(1024) void k_fsa(const int* __restrict__ Epk,
                                              const int* __restrict__ R,
                                              const unsigned* __restrict__ smax,
                                              const float* __restrict__ init_w,
                                              const float* __restrict__ fin_w,
                                              const int* __restrict__ xs,
                                              float* __restrict__ out) {
    __shared__ __align__(16) float alpha[QN];
    __shared__ __align__(16) int   qa[QN / 4];       // int8-packed (alpha - mu)/sa
    __shared__ int   xs_l[TN];
    __shared__ int   ipart[QN];
    __shared__ float wsum[8];

    const int t    = threadIdx.x;
    const int b    = blockIdx.x;
    const int i    = t & 511;
    const int jh   = t >> 9;                          // 0: j in [0,256), 1: [256,512)
    const int lane = t & 63, wave = t >> 6;

    if (t < TN) xs_l[t] = xs[b * TN + t];
    if (jh == 0) {
        float a0 = expf(init_w[i]);
        alpha[i] = a0;
        float ws = wave_sum(a0);
        if (lane == 0) wsum[wave] = ws;
    }
    __syncthreads();

    const float c  = 1.0f / 512.0f;
    const float Kq = 0.125f;                          // fixed conservative a-scale

    for (int step = 0; step < TN; ++step) {
        const int s = xs_l[step];
        float m = 0.0f;
        #pragma unroll
        for (int w = 0; w < 8; ++w) m += wsum[w];
        const float mu     = m * (1.0f / 512.0f);
        const float sa     = mu * (Kq / 127.0f);
        const float inv_sa = 127.0f / (Kq * mu);

        if (t < 128) {                                // pack qa from LDS alpha
            float4 av = ((const float4*)alpha)[t];
            int q0 = (int)rintf(fminf(fmaxf((av.x - mu) * inv_sa, -127.0f), 127.0f));
            int q1 = (int)rintf(fminf(fmaxf((av.y - mu) * inv_sa, -127.0f), 127.0f));
            int q2 = (int)rintf(fminf(fmaxf((av.z - mu) * inv_sa, -127.0f), 127.0f));
            int q3 = (int)rintf(fminf(fmaxf((av.w - mu) * inv_sa, -127.0f), 127.0f));
            qa[t] = (q0 & 255) | ((q1 & 255) << 8) | ((q2 & 255) << 16) | ((q3 & 255) << 24);
        }
        __syncthreads();

        // int8 dot: this thread's half of row i
        const int4* Ep = (const int4*)Epk + ((size_t)s * 32 + jh * 16) * 512 + i;
        const int4* qp = (const int4*)qa + jh * 16;
        int acc = 0;
        #pragma unroll
        for (int k = 0; k < 16; ++k) {
            int4 e = Ep[(size_t)k * 512];
            int4 q = qp[k];
            acc = SDOT4(e.x, q.x, acc);
            acc = SDOT4(e.y, q.y, acc);
            acc = SDOT4(e.z, q.z, acc);
            acc = SDOT4(e.w, q.w, acc);
        }
        if (jh == 1) ipart[i] = acc;
        __syncthreads();

        if (jh == 0) {
            const float se = __uint_as_float(smax[s]) * (1.0f / 127.0f);
            const int   Ri = R[(s << 9) + i];
            float outv = c * m + se * (mu * (float)Ri + sa * (float)(acc + ipart[i]));
            alpha[i] = outv;
            float ws = wave_sum(outv);
            if (lane == 0) wsum[wave] = ws;
        }
        __syncthreads();
    }

    // finalize: log(sum_i alpha_i * exp(final_i))
    if (jh == 0) {
        float v = alpha[i] * expf(fin_w[i]);
        float ws = wave_sum(v);
        if (lane == 0) wsum[wave] = ws;
    }
    __syncthreads();
    if (t == 0) {
        float m = 0.0f;
        #pragma unroll
        for (int w = 0; w < 8; ++w) m += wsum[w];
        out[b] = logf(m);
    }
}

extern "C" void kernel_launch(void* const* d_in, const int* in_sizes, int n_in,
                              void* d_out, int out_size, void* d_ws, size_t ws_size,
                              hipStream_t stream) {
    const float* A      = (const float*)d_in[0];   // (Q, S, Q) fp32 log-weights
    const float* init_w = (const float*)d_in[1];   // (Q,)
    const float* fin_w  = (const float*)d_in[2];   // (Q,)
    const int*   xs     = (const int*)d_in[3];     // (B, T) int32
    float* out = (float*)d_out;                    // (B,) fp32

    char* ws = (char*)d_ws;
    int*      Epk  = (int*)ws;                               // 16 MiB
    int*      R    = (int*)(ws + (16u << 20));               // 128 KiB
    unsigned* smax = (unsigned*)(ws + (16u << 20) + (128u << 10)); // 256 B

    hipMemsetAsync(smax, 0, 64 * sizeof(unsigned), stream);
    k_absmax<<<4096, 512, 0, stream>>>(A, smax);
    k_quant<<<512, 256, 0, stream>>>(A, smax, Epk, R);
    k_fsa<<<BN, 1024, 0, stream>>>(Epk, R, smax, init_w, fin_w, xs, out);
}

// Round 2
// 1162.483 us; speedup vs baseline: 1.0011x; 1.0011x over previous
//
#include <hip/hip_runtime.h>

// Problem constants (from reference): Q=512 states, S=64 symbols, B=64, T=256.
#define QN 512
#define SN 64
#define BN 64
#define TN 256

// ---- int8 dot4 (v_dot4_i32_i8) with software fallback ----
#if defined(__has_builtin)
#if __has_builtin(__builtin_amdgcn_sdot4)
#define SDOT4(a, b, c) __builtin_amdgcn_sdot4((a), (b), (c), false)
#endif
#endif
#ifndef SDOT4
static __device__ __forceinline__ int sdot4_sw(int a, int b, int c) {
    c += (int)(signed char)(a)       * (int)(signed char)(b);
    c += (int)(signed char)(a >> 8)  * (int)(signed char)(b >> 8);
    c += (int)(signed char)(a >> 16) * (int)(signed char)(b >> 16);
    c += (int)(signed char)(a >> 24) * (int)(signed char)(b >> 24);
    return c;
}
#define SDOT4(a, b, c) sdot4_sw((a), (b), (c))
#endif

static __device__ __forceinline__ float wave_sum(float v) {
    #pragma unroll
    for (int o = 32; o > 0; o >>= 1) v += __shfl_xor(v, o, 64);
    return v;
}
static __device__ __forceinline__ float wave_max(float v) {
    #pragma unroll
    for (int o = 32; o > 0; o >>= 1) v = fmaxf(v, __shfl_xor(v, o, 64));
    return v;
}

// Barrier with LDS-only drain: waits lgkmcnt(0) but leaves global loads in
// flight (vmcnt untouched) so the cross-step register prefetch survives the
// barrier. imm encoding (gfx9/CDNA): vm[3:0]=0xF, exp[6:4]=7, lgkm[11:8]=0,
// vm[15:14]=3  -> 0xC07F.
static __device__ __forceinline__ void barrier_lds(void) {
    __builtin_amdgcn_s_waitcnt(0xC07F);
    __builtin_amdgcn_s_barrier();
}

// ---- Kernel A: per-symbol bound of |E| = |exp(A) - 1/Q| via min/max of A ----
// E is monotone in A, so se = max(exp(amax)-c, c-exp(amin)): only 2 expf/block.
__global__ __launch_bounds__(256) void k_minmax(const float* __restrict__ A,
                                                unsigned* __restrict__ smax) {
    const int s  = blockIdx.x >> 3;
    const int i0 = (blockIdx.x & 7) * 64;
    const int tl = threadIdx.x & 127;     // float4 index within a row
    const int rh = threadIdx.x >> 7;      // row parity
    float mx = -1e30f, mn = 1e30f;
    for (int ro = 0; ro < 64; ro += 2) {
        const int i = i0 + ro + rh;
        float4 a4 = ((const float4*)A)[(size_t)(i * 64 + s) * 128 + tl];
        mx = fmaxf(mx, fmaxf(fmaxf(a4.x, a4.y), fmaxf(a4.z, a4.w)));
        mn = fminf(mn, fminf(fminf(a4.x, a4.y), fminf(a4.z, a4.w)));
    }
    mx = wave_max(mx);
    mn = -wave_max(-mn);
    if ((threadIdx.x & 63) == 0) {
        const float c = 1.0f / 512.0f;
        float se = fmaxf(expf(mx) - c, c - expf(mn));
        atomicMax(&smax[s], __float_as_uint(se));   // se > 0: uint order == float order
    }
}

// ---- Kernel B: quantize E to int8, pack transposed layout + rowsums ----
// Epk (int32 units): ((s*32 + j16)*512 + i)*4 + w holds bytes for
// j = 16*j16 + 4*w + {0..3} at state i -> int4 load = 16 consecutive j for one i.
__global__ __launch_bounds__(256) void k_quant(const float* __restrict__ A,
                                               const unsigned* __restrict__ smax,
                                               int* __restrict__ Epk,
                                               int* __restrict__ R) {
    __shared__ int tile[64][129];
    const int s  = blockIdx.x >> 3;
    const int i0 = (blockIdx.x & 7) * 64;
    const float se  = __uint_as_float(smax[s]);
    const float inv = se > 0.0f ? 127.0f / se : 0.0f;
    const float c = 1.0f / 512.0f;
    const int tl = threadIdx.x & 127;
    const int rh = threadIdx.x >> 7;
    for (int ro = 0; ro < 64; ro += 2) {
        const int r = ro + rh;
        const int i = i0 + r;
        float4 a4 = ((const float4*)A)[(size_t)(i * 64 + s) * 128 + tl];
        int q0 = (int)rintf(fminf(fmaxf((expf(a4.x) - c) * inv, -127.0f), 127.0f));
        int q1 = (int)rintf(fminf(fmaxf((expf(a4.y) - c) * inv, -127.0f), 127.0f));
        int q2 = (int)rintf(fminf(fmaxf((expf(a4.z) - c) * inv, -127.0f), 127.0f));
        int q3 = (int)rintf(fminf(fmaxf((expf(a4.w) - c) * inv, -127.0f), 127.0f));
        tile[r][tl] = (q0 & 255) | ((q1 & 255) << 8) | ((q2 & 255) << 16) | ((q3 & 255) << 24);
    }
    __syncthreads();
    if (threadIdx.x < 64) {
        const int r = threadIdx.x;
        int acc = 0;
        #pragma unroll 8
        for (int k = 0; k < 128; ++k) acc = SDOT4(tile[r][k], 0x01010101, acc);
        R[(s << 9) + i0 + r] = acc;
    }
    const int il = threadIdx.x & 63;
    const int jg = threadIdx.x >> 6;
    for (int jo = 0; jo < 8; ++jo) {
        const int j16 = jg * 8 + jo;
        int4 v;
        v.x = tile[il][j16 * 4 + 0];
        v.y = tile[il][j16 * 4 + 1];
        v.z = tile[il][j16 * 4 + 2];
        v.w = tile[il][j16 * 4 + 3];
        ((int4*)Epk)[((size_t)(s * 32 + j16) * 512) + i0 + il] = v;
    }
}

// ---- Main kernel: one block per batch; pipelined register prefetch ----
// Thread t handles row irow = t>>1, j-half jhalf = t&1 (pair combines via
// shfl_xor(1) -> no ipart LDS exchange, 2 barriers/step).
__global__ __launch_bounds__(1024) void k_fsa(const int* __restrict__ Epk,
                                              const int* __restrict__ R,
                                              const unsigned* __restrict__ smax,
                                              const float* __restrict__ init_w,
                                              const float* __restrict__ fin_w,
                                              const int* __restrict__ xs,
                                              float* __restrict__ out) {
    __shared__ __align__(16) float alpha[QN];
    __shared__ __align__(16) int   qa[QN / 4];
    __shared__ int   xs_l[TN];
    __shared__ float wsum[16];
    __shared__ float se_l[SN];

    const int t = threadIdx.x, b = blockIdx.x;
    const int lane = t & 63, wave = t >> 6;
    const int jhalf = t & 1;
    const int irow  = t >> 1;

    if (t < TN) xs_l[t] = xs[b * TN + t];
    if (t < SN) se_l[t] = __uint_as_float(smax[t]) * (1.0f / 127.0f);
    if (t < QN) {
        float a0 = expf(init_w[t]);
        alpha[t] = a0;
        float ws = wave_sum(a0);
        if (lane == 0) wsum[wave] = ws;
    } else if (lane == 0) {
        wsum[wave] = 0.0f;
    }

    // prefetch step 0 (read symbol straight from global; xs_l not visible yet)
    const int s0 = xs[b * TN];
    const int4* __restrict__ Epb = (const int4*)Epk;
    int4 e[16];
    {
        const int4* Ep = Epb + ((size_t)(s0 * 32 + jhalf * 16)) * 512 + irow;
        #pragma unroll
        for (int k = 0; k < 16; ++k) e[k] = Ep[(size_t)k * 512];
    }
    int Rv = (jhalf == 0) ? R[(s0 << 9) + irow] : 0;

    barrier_lds();

    const float c  = 1.0f / 512.0f;
    const float Kq = 0.125f;

    for (int step = 0; step < TN; ++step) {
        const int s      = xs_l[step];
        const int s_next = xs_l[(step + 1) & (TN - 1)];   // wraps: dummy prefetch at end
        float m = 0.0f;
        #pragma unroll
        for (int w = 0; w < 16; ++w) m += wsum[w];
        const float mu     = m * (1.0f / 512.0f);
        const float sa     = mu * (Kq / 127.0f);
        const float inv_sa = 127.0f / (Kq * mu);

        if (t < 128) {
            float4 av = ((const float4*)alpha)[t];
            int q0 = (int)rintf(fminf(fmaxf((av.x - mu) * inv_sa, -127.0f), 127.0f));
            int q1 = (int)rintf(fminf(fmaxf((av.y - mu) * inv_sa, -127.0f), 127.0f));
            int q2 = (int)rintf(fminf(fmaxf((av.z - mu) * inv_sa, -127.0f), 127.0f));
            int q3 = (int)rintf(fminf(fmaxf((av.w - mu) * inv_sa, -127.0f), 127.0f));
            qa[t] = (q0 & 255) | ((q1 & 255) << 8) | ((q2 & 255) << 16) | ((q3 & 255) << 24);
        }
        barrier_lds();

        // dots on prefetched registers; immediately re-issue each slot for s_next
        const int4* qp  = (const int4*)qa + jhalf * 16;
        const int4* Epn = Epb + ((size_t)(s_next * 32 + jhalf * 16)) * 512 + irow;
        int acc0 = 0, acc1 = 0, acc2 = 0, acc3 = 0;
        #pragma unroll
        for (int k = 0; k < 16; ++k) {
            int4 q = qp[k];
            acc0 = SDOT4(e[k].x, q.x, acc0);
            acc1 = SDOT4(e[k].y, q.y, acc1);
            acc2 = SDOT4(e[k].z, q.z, acc2);
            acc3 = SDOT4(e[k].w, q.w, acc3);
            e[k] = Epn[(size_t)k * 512];
        }
        int acc = (acc0 + acc1) + (acc2 + acc3);
        acc += __shfl_xor(acc, 1);                        // combine row's two halves

        const int RvC = Rv;
        if (jhalf == 0) Rv = R[(s_next << 9) + irow];     // prefetch next R

        float outv = 0.0f;
        if (jhalf == 0) {
            const float se = se_l[s];
            outv = c * m + se * (mu * (float)RvC + sa * (float)acc);
            alpha[irow] = outv;
        }
        float ws = wave_sum(jhalf == 0 ? outv : 0.0f);
        if (lane == 0) wsum[wave] = ws;
        barrier_lds();
    }

    // finalize: log(sum_i alpha_i * exp(final_i))
    if (t < QN) {
        float v = alpha[t] * expf(fin_w[t]);
        float ws = wave_sum(v);
        if (lane == 0) wsum[wave] = ws;
    } else if (lane == 0) {
        wsum[wave] = 0.0f;
    }
    barrier_lds();
    if (t == 0) {
        float m = 0.0f;
        #pragma unroll
        for (int w = 0; w < 16; ++w) m += wsum[w];
        out[b] = logf(m);
    }
}

extern "C" void kernel_launch(void* const* d_in, const int* in_sizes, int n_in,
                              void* d_out, int out_size, void* d_ws, size_t ws_size,
                              hipStream_t stream) {
    const float* A      = (const float*)d_in[0];   // (Q, S, Q) fp32 log-weights
    const float* init_w = (const float*)d_in[1];   // (Q,)
    const float* fin_w  = (const float*)d_in[2];   // (Q,)
    const int*   xs     = (const int*)d_in[3];     // (B, T) int32
    float* out = (float*)d_out;                    // (B,) fp32

    char* ws = (char*)d_ws;
    int*      Epk  = (int*)ws;                               // 16 MiB
    int*      R    = (int*)(ws + (16u << 20));               // 128 KiB
    unsigned* smax = (unsigned*)(ws + (16u << 20) + (128u << 10)); // 256 B

    hipMemsetAsync(smax, 0, 64 * sizeof(unsigned), stream);
    k_minmax<<<512, 256, 0, stream>>>(A, smax);
    k_quant<<<512, 256, 0, stream>>>(A, smax, Epk, R);
    k_fsa<<<BN, 1024, 0, stream>>>(Epk, R, smax, init_w, fin_w, xs, out);
}